// Round 1
// baseline (37.073 us; speedup 1.0000x reference)
//
#include <hip/hip_runtime.h>

#define NN 4
#define CC 128
#define HH 64
#define WW 64
#define KK 5
#define K2 25
#define HUP 128
#define WUP 128

// grid: NN*HH*4 = 1024 blocks, 256 threads.
// block: cq = bid&3 (channel quarter), h = (bid>>2)&63, n = bid>>8
// thread: w = t&63 (output w pair 2w,2w+1), cg = t>>6; channels c = cq*32 + ci*4 + cg
__global__ __launch_bounds__(256) void carafe_kernel(
    const float* __restrict__ feat, const float* __restrict__ masks,
    float* __restrict__ out) {
  const int bid = blockIdx.x;
  const int cq = bid & 3;
  const int h  = (bid >> 2) & (HH - 1);
  const int n  = bid >> 8;
  const int t  = threadIdx.x;
  const int w  = t & (WW - 1);
  const int cg = t >> 6;

  // Clamped window offsets + validity (OOB handled by zeroing the mask regs,
  // so the hot loop has no branches and loads stay in-bounds).
  int roff[KK], xoff[KK];
  float vi[KK], vj[KK];
#pragma unroll
  for (int i = 0; i < KK; ++i) {
    int r = h - 2 + i;
    vi[i] = (r >= 0 && r < HH) ? 1.f : 0.f;
    r = min(max(r, 0), HH - 1);
    roff[i] = r * WW;
    int x = w - 2 + i;
    vj[i] = (x >= 0 && x < WW) ? 1.f : 0.f;
    x = min(max(x, 0), WW - 1);
    xoff[i] = x;
  }

  // Masks into registers: mreg[k][a][b] = masks[n,k,2h+a,2w+b] * valid(i,j).
  // Reused across all 32 channels this block handles.
  float mreg[K2][2][2];
#pragma unroll
  for (int k = 0; k < K2; ++k) {
    const int i = k / KK, j = k % KK;
    const float vv = vi[i] * vj[j];
#pragma unroll
    for (int a = 0; a < 2; ++a) {
      const float2 mv = *reinterpret_cast<const float2*>(
          &masks[(((size_t)n * K2 + k) * HUP + (2 * h + a)) * WUP + 2 * w]);
      mreg[k][a][0] = mv.x * vv;
      mreg[k][a][1] = mv.y * vv;
    }
  }

  int c = cq * 32 + cg;
  const float* fb = feat + (size_t)(n * CC + c) * (HH * WW);
  float* ob = out + ((size_t)(n * CC + c) * HUP + 2 * h) * WUP + 2 * w;

  for (int ci = 0; ci < 8; ++ci) {
    // 5x5 feature window (L1-resident; wave-uniform base + lane offsets).
    float f[KK][KK];
#pragma unroll
    for (int i = 0; i < KK; ++i)
#pragma unroll
      for (int j = 0; j < KK; ++j)
        f[i][j] = fb[roff[i] + xoff[j]];

    float acc[2][2] = {{0.f, 0.f}, {0.f, 0.f}};
#pragma unroll
    for (int k = 0; k < K2; ++k) {
      const int i = k / KK, j = k % KK;
      acc[0][0] += f[i][j] * mreg[k][0][0];
      acc[0][1] += f[i][j] * mreg[k][0][1];
      acc[1][0] += f[i][j] * mreg[k][1][0];
      acc[1][1] += f[i][j] * mreg[k][1][1];
    }

    *reinterpret_cast<float2*>(&ob[0])   = make_float2(acc[0][0], acc[0][1]);
    *reinterpret_cast<float2*>(&ob[WUP]) = make_float2(acc[1][0], acc[1][1]);

    fb += 4 * (HH * WW);        // channel stride 4 (cg-interleaved)
    ob += (size_t)4 * HUP * WUP;
  }
}

extern "C" void kernel_launch(void* const* d_in, const int* in_sizes, int n_in,
                              void* d_out, int out_size, void* d_ws, size_t ws_size,
                              hipStream_t stream) {
  const float* feat  = (const float*)d_in[0];
  const float* masks = (const float*)d_in[1];
  float* out = (float*)d_out;
  (void)in_sizes; (void)n_in; (void)out_size; (void)d_ws; (void)ws_size;
  carafe_kernel<<<NN * HH * 4, 256, 0, stream>>>(feat, masks, out);
}

// Round 2
// 27.887 us; speedup vs baseline: 1.3294x; 1.3294x over previous
//
#include <hip/hip_runtime.h>

#define NN 4
#define CC 128
#define HH 64
#define WW 64
#define KK 5
#define K2 25
#define HUP 128
#define WUP 128

typedef int v4i __attribute__((ext_vector_type(4)));

// CK-style raw buffer load: HW bounds-check (OOB -> 0.0f), 12-bit imm offset
// folded from constant adds on voffset.
__device__ float llvm_amdgcn_raw_buffer_load_fp32(v4i srsrc, int voffset,
                                                  int soffset, int aux)
    __asm("llvm.amdgcn.raw.buffer.load.f32");

__device__ inline v4i make_srd(const void* p, unsigned bytes) {
  union { const void* p; unsigned u[2]; } a;
  a.p = p;
  v4i r;
  r.x = (int)a.u[0];
  r.y = (int)(a.u[1] & 0xffffu);  // base[47:32], stride=0
  r.z = (int)bytes;               // num_records in bytes (stride==0)
  r.w = 0x00020000;               // raw dword access
  return r;
}

// grid: NN*HH*4 = 1024 blocks, 256 threads, 3 blocks/CU target.
// block: cq = bid&3 (channel quarter), h = (bid>>2)&63, n = bid>>8
// thread: w = t&63 (output w pair 2w,2w+1), cg = t>>6; channels c = cq*32+ci*4+cg
__global__ __launch_bounds__(256, 3) void carafe_kernel(
    const float* __restrict__ feat, const float* __restrict__ masks,
    float* __restrict__ out) {
  const int bid = blockIdx.x;
  const int cq = bid & 3;
  const int h  = (bid >> 2) & (HH - 1);
  const int n  = bid >> 8;
  const int t  = threadIdx.x;
  const int w  = t & (WW - 1);
  const int cg = t >> 6;

  // Validity for logical zero-padding at the h/w edges (folded into masks;
  // buffer OOB->0 additionally covers the physical buffer ends).
  float vi[KK], vj[KK];
#pragma unroll
  for (int i = 0; i < KK; ++i) {
    const int r = h - 2 + i;
    vi[i] = (r >= 0 && r < HH) ? 1.f : 0.f;
    const int x = w - 2 + i;
    vj[i] = (x >= 0 && x < WW) ? 1.f : 0.f;
  }

  // Masks into registers: mreg[k][a][b] = masks[n,k,2h+a,2w+b] * valid(i,j).
  float mreg[K2][2][2];
#pragma unroll
  for (int k = 0; k < K2; ++k) {
    const int i = k / KK, j = k % KK;
    const float vv = vi[i] * vj[j];
#pragma unroll
    for (int a = 0; a < 2; ++a) {
      const float2 mv = *reinterpret_cast<const float2*>(
          &masks[(((size_t)n * K2 + k) * HUP + (2 * h + a)) * WUP + 2 * w]);
      mreg[k][a][0] = mv.x * vv;
      mreg[k][a][1] = mv.y * vv;
    }
  }

  const v4i srd = make_srd(feat, (unsigned)(NN * CC * HH * WW) * 4u);

  const int c = cq * 32 + cg;
  // Byte offset of window origin (h-2, w-2) in this thread's first channel.
  // May go "negative" -> wraps unsigned -> OOB -> 0 (matches zero padding).
  int vbase = (((n * CC + c) * HH * WW) + (h - 2) * WW + (w - 2)) * 4;
  float* ob = out + ((size_t)(n * CC + c) * HUP + 2 * h) * WUP + 2 * w;

  for (int ci = 0; ci < 8; ++ci) {
    float f[KK][KK];
#pragma unroll
    for (int i = 0; i < KK; ++i)
#pragma unroll
      for (int j = 0; j < KK; ++j)
        f[i][j] = llvm_amdgcn_raw_buffer_load_fp32(
            srd, vbase + (i * WW + j) * 4, 0, 0);

    float acc[2][2] = {{0.f, 0.f}, {0.f, 0.f}};
#pragma unroll
    for (int k = 0; k < K2; ++k) {
      const int i = k / KK, j = k % KK;
      acc[0][0] += f[i][j] * mreg[k][0][0];
      acc[0][1] += f[i][j] * mreg[k][0][1];
      acc[1][0] += f[i][j] * mreg[k][1][0];
      acc[1][1] += f[i][j] * mreg[k][1][1];
    }

    *reinterpret_cast<float2*>(&ob[0])   = make_float2(acc[0][0], acc[0][1]);
    *reinterpret_cast<float2*>(&ob[WUP]) = make_float2(acc[1][0], acc[1][1]);

    vbase += 4 * HH * WW * 4;        // +4 channels (cg-interleaved), bytes
    ob += (size_t)4 * HUP * WUP;
  }
}

extern "C" void kernel_launch(void* const* d_in, const int* in_sizes, int n_in,
                              void* d_out, int out_size, void* d_ws, size_t ws_size,
                              hipStream_t stream) {
  const float* feat  = (const float*)d_in[0];
  const float* masks = (const float*)d_in[1];
  float* out = (float*)d_out;
  (void)in_sizes; (void)n_in; (void)out_size; (void)d_ws; (void)ws_size;
  carafe_kernel<<<NN * HH * 4, 256, 0, stream>>>(feat, masks, out);
}

// Round 3
// 23.877 us; speedup vs baseline: 1.5527x; 1.1679x over previous
//
#include <hip/hip_runtime.h>

#define NN 4
#define CC 128
#define HH 64
#define WW 64
#define KK 5
#define K2 25
#define HUP 128
#define WUP 128

typedef int   v4i __attribute__((ext_vector_type(4)));
typedef float v4f __attribute__((ext_vector_type(4)));
typedef float v2f __attribute__((ext_vector_type(2)));

// Raw buffer loads: HW bounds-check (OOB -> 0.0f).
__device__ float llvm_amdgcn_raw_buffer_load_fp32(v4i srsrc, int voffset,
                                                  int soffset, int aux)
    __asm("llvm.amdgcn.raw.buffer.load.f32");
__device__ v4f llvm_amdgcn_raw_buffer_load_v4f32(v4i srsrc, int voffset,
                                                 int soffset, int aux)
    __asm("llvm.amdgcn.raw.buffer.load.v4f32");

__device__ inline v4i make_srd(const void* p, unsigned bytes) {
  union { const void* p; unsigned u[2]; } a;
  a.p = p;
  v4i r;
  r.x = (int)a.u[0];
  r.y = (int)(a.u[1] & 0xffffu);  // base[47:32], stride=0
  r.z = (int)bytes;               // num_records in bytes
  r.w = 0x00020000;               // raw dword access
  return r;
}

// grid: NN*HH*4 = 1024 blocks, 256 threads.
// block: cq = bid&3, h = (bid>>2)&63, n = bid>>8
// thread: w = t&63 (output pair 2w,2w+1), cg = t>>6; c = cq*32 + ci*4 + cg
__global__ __launch_bounds__(256, 3) void carafe_kernel(
    const float* __restrict__ feat, const float* __restrict__ masks,
    float* __restrict__ out) {
  const int bid = blockIdx.x;
  const int cq = bid & 3;
  const int h  = (bid >> 2) & (HH - 1);
  const int n  = bid >> 8;
  const int t  = threadIdx.x;
  const int w  = t & (WW - 1);
  const int cg = t >> 6;

  // Validity of window taps (zero-padding folded into the mask registers).
  float vi[KK], vj[KK];
#pragma unroll
  for (int i = 0; i < KK; ++i) {
    const int r = h - 2 + i;
    vi[i] = (r >= 0 && r < HH) ? 1.f : 0.f;
    const int x = w - 2 + i;
    vj[i] = (x >= 0 && x < WW) ? 1.f : 0.f;
  }

  // mreg[k][a] = {masks[n,k,2h+a,2w], masks[n,k,2h+a,2w+1]} * valid(i,j)
  // float2 layout so the FMA loop packs into v_pk_fma_f32.
  v2f mreg[K2][2];
#pragma unroll
  for (int k = 0; k < K2; ++k) {
    const int i = k / KK, j = k % KK;
    const float vv = vi[i] * vj[j];
#pragma unroll
    for (int a = 0; a < 2; ++a) {
      const float2 mv = *reinterpret_cast<const float2*>(
          &masks[(((size_t)n * K2 + k) * HUP + (2 * h + a)) * WUP + 2 * w]);
      v2f m; m.x = mv.x * vv; m.y = mv.y * vv;
      mreg[k][a] = m;
    }
  }

  const v4i srd = make_srd(feat, (unsigned)(NN * CC * HH * WW) * 4u);
  const int c = cq * 32 + cg;
  // Byte offset of window origin (h-2, w-2); negative only when c==0 (ci==0).
  int vbase = (((n * CC + c) * HH * WW) + (h - 2) * WW + (w - 2)) * 4;
  float* ob = out + ((size_t)(n * CC + c) * HUP + 2 * h) * WUP + 2 * w;

  // --- ci = 0: scalar loads. Safe for the buffer-start underflow case
  // (negative voffset -> OOB -> 0, and those taps are mask-zeroed). ---
  {
    float f[K2];
#pragma unroll
    for (int i = 0; i < KK; ++i)
#pragma unroll
      for (int j = 0; j < KK; ++j)
        f[i * KK + j] = llvm_amdgcn_raw_buffer_load_fp32(
            srd, vbase + (i * WW + j) * 4, 0, 0);

    v2f acc0 = {0.f, 0.f}, acc1 = {0.f, 0.f};
#pragma unroll
    for (int k = 0; k < K2; ++k) {
      v2f ff; ff.x = f[k]; ff.y = f[k];
      acc0 += ff * mreg[k][0];
      acc1 += ff * mreg[k][1];
    }
    *reinterpret_cast<v2f*>(&ob[0])   = acc0;
    *reinterpret_cast<v2f*>(&ob[WUP]) = acc1;
  }

  // --- ci = 1..7: c >= 4 so every row voffset is positive; row/channel
  // crossings at w/h edges read in-bounds garbage that the validity-zeroed
  // masks annihilate. One dwordx4 + one dword per window row. ---
#pragma unroll 1
  for (int ci = 1; ci < 8; ++ci) {
    vbase += 4 * HH * WW * 4;  // +4 channels (cg-interleaved), bytes
    ob += (size_t)4 * HUP * WUP;

    float f[K2];
#pragma unroll
    for (int i = 0; i < KK; ++i) {
      const int vo = vbase + i * WW * 4;
      const v4f r4 = llvm_amdgcn_raw_buffer_load_v4f32(srd, vo, 0, 0);
      f[i * KK + 0] = r4.x;
      f[i * KK + 1] = r4.y;
      f[i * KK + 2] = r4.z;
      f[i * KK + 3] = r4.w;
      f[i * KK + 4] = llvm_amdgcn_raw_buffer_load_fp32(srd, vo + 16, 0, 0);
    }

    v2f acc0 = {0.f, 0.f}, acc1 = {0.f, 0.f};
#pragma unroll
    for (int k = 0; k < K2; ++k) {
      v2f ff; ff.x = f[k]; ff.y = f[k];
      acc0 += ff * mreg[k][0];
      acc1 += ff * mreg[k][1];
    }
    *reinterpret_cast<v2f*>(&ob[0])   = acc0;
    *reinterpret_cast<v2f*>(&ob[WUP]) = acc1;
  }
}

extern "C" void kernel_launch(void* const* d_in, const int* in_sizes, int n_in,
                              void* d_out, int out_size, void* d_ws, size_t ws_size,
                              hipStream_t stream) {
  const float* feat  = (const float*)d_in[0];
  const float* masks = (const float*)d_in[1];
  float* out = (float*)d_out;
  (void)in_sizes; (void)n_in; (void)out_size; (void)d_ws; (void)ws_size;
  carafe_kernel<<<NN * HH * 4, 256, 0, stream>>>(feat, masks, out);
}

// Round 4
// 23.826 us; speedup vs baseline: 1.5560x; 1.0021x over previous
//
#include <hip/hip_runtime.h>

#define NN 4
#define CC 128
#define HH 64
#define WW 64
#define KK 5
#define K2 25
#define HUP 128
#define WUP 128

typedef int   v4i __attribute__((ext_vector_type(4)));
typedef float v4f __attribute__((ext_vector_type(4)));
typedef float v2f __attribute__((ext_vector_type(2)));

// Raw buffer ops: HW bounds-check (OOB load -> 0.0f, OOB store dropped).
__device__ float llvm_amdgcn_raw_buffer_load_fp32(v4i srsrc, int voffset,
                                                  int soffset, int aux)
    __asm("llvm.amdgcn.raw.buffer.load.f32");
__device__ v4f llvm_amdgcn_raw_buffer_load_v4f32(v4i srsrc, int voffset,
                                                 int soffset, int aux)
    __asm("llvm.amdgcn.raw.buffer.load.v4f32");
__device__ void llvm_amdgcn_raw_buffer_store_v2f32(v2f data, v4i srsrc,
                                                   int voffset, int soffset,
                                                   int aux)
    __asm("llvm.amdgcn.raw.buffer.store.v2f32");

__device__ inline v4i make_srd(const void* p, unsigned bytes) {
  union { const void* p; unsigned u[2]; } a;
  a.p = p;
  v4i r;
  r.x = (int)a.u[0];
  r.y = (int)(a.u[1] & 0xffffu);  // base[47:32], stride=0
  r.z = (int)bytes;               // num_records in bytes
  r.w = 0x00020000;               // raw dword access
  return r;
}

// grid: NN*HH*4 = 1024 blocks, 256 threads, 4 blocks/CU (VGPR<=128) so all
// 4096 waves are co-resident in a single scheduling round.
// block: cq = bid&3, h = (bid>>2)&63, n = bid>>8
// thread: w = t&63 (output pair 2w,2w+1), cg = t>>6; c = cq*32 + ci*4 + cg
__global__ __launch_bounds__(256, 4) void carafe_kernel(
    const float* __restrict__ feat, const float* __restrict__ masks,
    float* __restrict__ out) {
  const int bid = blockIdx.x;
  const int cq = bid & 3;
  const int h  = (bid >> 2) & (HH - 1);
  const int n  = bid >> 8;
  const int t  = threadIdx.x;
  const int w  = t & (WW - 1);
  const int cg = t >> 6;

  // Validity of window taps (zero-padding folded into the mask registers).
  float vi[KK], vj[KK];
#pragma unroll
  for (int i = 0; i < KK; ++i) {
    const int r = h - 2 + i;
    vi[i] = (r >= 0 && r < HH) ? 1.f : 0.f;
    const int x = w - 2 + i;
    vj[i] = (x >= 0 && x < WW) ? 1.f : 0.f;
  }

  // mreg[k][a] = {masks[n,k,2h+a,2w], masks[n,k,2h+a,2w+1]} * valid(i,j)
  v2f mreg[K2][2];
#pragma unroll
  for (int k = 0; k < K2; ++k) {
    const int i = k / KK, j = k % KK;
    const float vv = vi[i] * vj[j];
#pragma unroll
    for (int a = 0; a < 2; ++a) {
      const float2 mv = *reinterpret_cast<const float2*>(
          &masks[(((size_t)n * K2 + k) * HUP + (2 * h + a)) * WUP + 2 * w]);
      v2f m; m.x = mv.x * vv; m.y = mv.y * vv;
      mreg[k][a] = m;
    }
  }

  const v4i srdF = make_srd(feat, (unsigned)(NN * CC * HH * WW) * 4u);
  const v4i srdO = make_srd(out, (unsigned)(NN * CC * HUP * WUP) * 4u);

  const int c = cq * 32 + cg;
  // Byte offset of window origin (h-2, w-2); negative only when c==0 (ci==0).
  int vfb = (((n * CC + c) * HH * WW) + (h - 2) * WW + (w - 2)) * 4;
  int vob = (((n * CC + c) * HUP + 2 * h) * WUP + 2 * w) * 4;

#define FMA5(kb, e0, e1, e2, e3, e4)                                    \
  do {                                                                  \
    v2f ff;                                                             \
    ff.x = (e0); ff.y = (e0); acc0 += ff * mreg[(kb)+0][0]; acc1 += ff * mreg[(kb)+0][1]; \
    ff.x = (e1); ff.y = (e1); acc0 += ff * mreg[(kb)+1][0]; acc1 += ff * mreg[(kb)+1][1]; \
    ff.x = (e2); ff.y = (e2); acc0 += ff * mreg[(kb)+2][0]; acc1 += ff * mreg[(kb)+2][1]; \
    ff.x = (e3); ff.y = (e3); acc0 += ff * mreg[(kb)+3][0]; acc1 += ff * mreg[(kb)+3][1]; \
    ff.x = (e4); ff.y = (e4); acc0 += ff * mreg[(kb)+4][0]; acc1 += ff * mreg[(kb)+4][1]; \
  } while (0)

  // --- ci = 0: scalar taps, R3-proven addressing (negative voffset -> 0),
  // row-split (<=15 window regs live) to hold the 128-VGPR budget. ---
  {
    v2f acc0 = {0.f, 0.f}, acc1 = {0.f, 0.f};
    float fA[15];
#pragma unroll
    for (int i = 0; i < 3; ++i)
#pragma unroll
      for (int j = 0; j < KK; ++j)
        fA[i * KK + j] = llvm_amdgcn_raw_buffer_load_fp32(
            srdF, vfb + (i * WW + j) * 4, 0, 0);
    FMA5(0,  fA[0],  fA[1],  fA[2],  fA[3],  fA[4]);
    FMA5(5,  fA[5],  fA[6],  fA[7],  fA[8],  fA[9]);
    FMA5(10, fA[10], fA[11], fA[12], fA[13], fA[14]);

    float fB[10];
#pragma unroll
    for (int i = 0; i < 2; ++i)
#pragma unroll
      for (int j = 0; j < KK; ++j)
        fB[i * KK + j] = llvm_amdgcn_raw_buffer_load_fp32(
            srdF, vfb + ((i + 3) * WW + j) * 4, 0, 0);
    FMA5(15, fB[0], fB[1], fB[2], fB[3], fB[4]);
    FMA5(20, fB[5], fB[6], fB[7], fB[8], fB[9]);

    llvm_amdgcn_raw_buffer_store_v2f32(acc0, srdO, vob, 0, 0);
    llvm_amdgcn_raw_buffer_store_v2f32(acc1, srdO, vob + WUP * 4, 0, 0);
  }

  // --- ci = 1..7: c >= 4 so voffsets are positive; edge crossings read
  // in-bounds garbage annihilated by the validity-zeroed masks. ---
#pragma unroll 1
  for (int ci = 1; ci < 8; ++ci) {
    vfb += 4 * HH * WW * 4;    // +4 channels, bytes
    vob += 4 * HUP * WUP * 4;

    v2f acc0 = {0.f, 0.f}, acc1 = {0.f, 0.f};

    // rows 0..2 (6 VMEM, 15 regs), then FMA k=0..14
    const v4f r0 = llvm_amdgcn_raw_buffer_load_v4f32(srdF, vfb + 0 * WW * 4, 0, 0);
    const float s0 = llvm_amdgcn_raw_buffer_load_fp32(srdF, vfb + 0 * WW * 4 + 16, 0, 0);
    const v4f r1 = llvm_amdgcn_raw_buffer_load_v4f32(srdF, vfb + 1 * WW * 4, 0, 0);
    const float s1 = llvm_amdgcn_raw_buffer_load_fp32(srdF, vfb + 1 * WW * 4 + 16, 0, 0);
    const v4f r2 = llvm_amdgcn_raw_buffer_load_v4f32(srdF, vfb + 2 * WW * 4, 0, 0);
    const float s2 = llvm_amdgcn_raw_buffer_load_fp32(srdF, vfb + 2 * WW * 4 + 16, 0, 0);
    FMA5(0,  r0.x, r0.y, r0.z, r0.w, s0);
    FMA5(5,  r1.x, r1.y, r1.z, r1.w, s1);
    FMA5(10, r2.x, r2.y, r2.z, r2.w, s2);

    // rows 3..4 (4 VMEM, 10 regs), then FMA k=15..24
    const v4f r3 = llvm_amdgcn_raw_buffer_load_v4f32(srdF, vfb + 3 * WW * 4, 0, 0);
    const float s3 = llvm_amdgcn_raw_buffer_load_fp32(srdF, vfb + 3 * WW * 4 + 16, 0, 0);
    const v4f r4 = llvm_amdgcn_raw_buffer_load_v4f32(srdF, vfb + 4 * WW * 4, 0, 0);
    const float s4 = llvm_amdgcn_raw_buffer_load_fp32(srdF, vfb + 4 * WW * 4 + 16, 0, 0);
    FMA5(15, r3.x, r3.y, r3.z, r3.w, s3);
    FMA5(20, r4.x, r4.y, r4.z, r4.w, s4);

    llvm_amdgcn_raw_buffer_store_v2f32(acc0, srdO, vob, 0, 0);
    llvm_amdgcn_raw_buffer_store_v2f32(acc1, srdO, vob + WUP * 4, 0, 0);
  }
#undef FMA5
}

extern "C" void kernel_launch(void* const* d_in, const int* in_sizes, int n_in,
                              void* d_out, int out_size, void* d_ws, size_t ws_size,
                              hipStream_t stream) {
  const float* feat  = (const float*)d_in[0];
  const float* masks = (const float*)d_in[1];
  float* out = (float*)d_out;
  (void)in_sizes; (void)n_in; (void)out_size; (void)d_ws; (void)ws_size;
  carafe_kernel<<<NN * HH * 4, 256, 0, stream>>>(feat, masks, out);
}